// Round 7
// baseline (113.064 us; speedup 1.0000x reference)
//
#include <hip/hip_runtime.h>
#include <math.h>

#define NATOMS    128
#define NSEG      7875     // segments: i in [0,124], j in [i+2,126]
#define PADLEN    8128     // (n*n-n)/2 over n=128 pairs; padded triu length
#define OUT_PER_B 16256    // 2 * PADLEN
#define NBANDS    4

// Balanced segment bands by i-row: C(i) = 125*i - i*(i-1)/2
// C(17)=1989, C(37)=3959, C(63)=5922. Counts: 1989/1970/1963/1953.
__constant__ int BAND_LO[NBANDS + 1] = {0, 1989, 3959, 5922, NSEG};

struct F3 { float x, y, z; };
__device__ __forceinline__ F3 f3sub(F3 a, F3 b) { return {a.x - b.x, a.y - b.y, a.z - b.z}; }
__device__ __forceinline__ F3 f3cross(F3 a, F3 b) {
    return {a.y * b.z - a.z * b.y, a.z * b.x - a.x * b.z, a.x * b.y - a.y * b.x};
}
__device__ __forceinline__ float f3dot(F3 a, F3 b) { return a.x * b.x + a.y * b.y + a.z * b.z; }
__device__ __forceinline__ float clip1(float x) { return fminf(1.0f, fmaxf(-1.0f, x)); }

// Branchless asin, A&S 4.4.46 (|err| ~ 2e-8); single v_sqrt_f32.
__device__ __forceinline__ float fast_asin(float x) {
    float a = fabsf(x);
    float p = -0.0012624911f;
    p = fmaf(p, a,  0.0066700901f);
    p = fmaf(p, a, -0.0170881256f);
    p = fmaf(p, a,  0.0308918810f);
    p = fmaf(p, a, -0.0501743046f);
    p = fmaf(p, a,  0.0889789874f);
    p = fmaf(p, a, -0.2145988016f);
    p = fmaf(p, a,  1.5707963050f);
    float r = 1.57079632679f - __builtin_amdgcn_sqrtf(1.0f - a) * p;
    return copysignf(r, x);
}

// u24 muls (full-rate v_mul_u32_u24; operands < 2^24 by construction).
__device__ __forceinline__ int seg_row_base(int i) { return 125 * i - (__umul24(i, i - 1) >> 1); }

// ---------------- Kernel 1: writhe per segment -> swr scratch ----------------
// grid = B * NBANDS small blocks; 256 thr; LDS 1.5 KB -> 8 blocks/CU, 32 waves.
__global__ __launch_bounds__(256, 8) void writhe_k1(
    const float* __restrict__ xyz,   // (B, 128, 3)
    float*       __restrict__ swr,   // base of scratch
    int                       swr_stride)  // floats per batch
{
    __shared__ float sx[NATOMS], sy[NATOMS], sz[NATOMS];

    const int bid  = blockIdx.x;
    const int b    = bid >> 2;
    const int band = bid & 3;
    const int t    = threadIdx.x;

    for (int u = t; u < 3 * NATOMS; u += 256) {
        float v = xyz[(size_t)b * (3 * NATOMS) + u];
        int a = u / 3, c = u - 3 * a;
        if (c == 0) sx[a] = v; else if (c == 1) sy[a] = v; else sz[a] = v;
    }
    __syncthreads();

    float* swr_b = swr + (size_t)b * swr_stride;
    const int lo = BAND_LO[band], hi = BAND_LO[band + 1];

    for (int s = lo + t; s < hi; s += 256) {
        // invert s -> (i,j): predicated fixups, u24 muls
        int i = (int)((251.0f - __builtin_amdgcn_sqrtf(63001.0f - 8.0f * (float)s)) * 0.5f);
        i = max(i, 0);
        i += (seg_row_base(i + 1) <= s);
        i += (seg_row_base(i + 1) <= s);
        i -= (seg_row_base(i) > s);
        i -= (seg_row_base(i) > s);
        int j = s - seg_row_base(i) + i + 2;

        F3 p0 = {sx[i],     sy[i],     sz[i]};
        F3 p1 = {sx[i + 1], sy[i + 1], sz[i + 1]};
        F3 p2 = {sx[j],     sy[j],     sz[j]};
        F3 p3 = {sx[j + 1], sy[j + 1], sz[j + 1]};

        // Unnormalized displacements (scale cancels inside unit(cross)).
        F3 u0 = f3sub(p2, p0);
        F3 u1 = f3sub(p3, p0);
        F3 u2 = f3sub(p2, p1);
        F3 u3 = f3sub(p3, p1);

        F3 n0 = f3cross(u0, u1);
        F3 n1 = f3cross(u1, u3);
        F3 n2 = f3cross(u3, u2);
        F3 n3 = f3cross(u2, u0);

        float q0 = f3dot(n0, n0);
        float q1 = f3dot(n1, n1);
        float q2 = f3dot(n2, n2);
        float q3 = f3dot(n3, n3);

        float c0 = clip1(f3dot(n0, n1) * __builtin_amdgcn_rsqf(q0 * q1));
        float c1 = clip1(f3dot(n1, n2) * __builtin_amdgcn_rsqf(q1 * q2));
        float c2 = clip1(f3dot(n2, n3) * __builtin_amdgcn_rsqf(q2 * q3));
        float c3 = clip1(f3dot(n3, n0) * __builtin_amdgcn_rsqf(q3 * q0));

        F3 axial = f3cross(f3sub(p3, p2), f3sub(p1, p0));
        float sd = f3dot(axial, u0);
        float sgn = (sd > 0.0f) ? 1.0f : ((sd < 0.0f) ? -1.0f : 0.0f);

        float omega = fast_asin(c0) + fast_asin(c1) + fast_asin(c2) + fast_asin(c3);
        swr_b[s] = omega * sgn * 0.15915494309189535f;  // / (2*pi)
    }
}

// ------------- Kernel 2: Laplacian gather + analytic permutation -------------
// out flat index k (per batch) is the 128x128 matrix row-major skipping the
// diagonal: r = k/127, c = k%127 + (k%127 >= r). p = pidx(min,max) selects the
// padded triu slot; slots p==0 and p==8127 are the zero pads. The 4
// contributing segments of slot (a,b) are (i,j) in {a-1,a}x{b-1,b}.
// sortv is not needed at all.
__global__ __launch_bounds__(1024, 8) void writhe_k2(
    const float* __restrict__ swr,
    int                       swr_stride,
    float*       __restrict__ out)   // (B, 16256)
{
    __shared__ float s_wr[NSEG];

    const int b = blockIdx.x;
    const int t = threadIdx.x;

    const float* swr_b = swr + (size_t)b * swr_stride;
    for (int s = t; s < NSEG; s += 1024) s_wr[s] = swr_b[s];
    __syncthreads();

    float* ob = out + (size_t)b * OUT_PER_B;
    for (int k = t; k < OUT_PER_B; k += 1024) {
        unsigned r  = (unsigned)k / 127u;
        unsigned cc = (unsigned)k - 127u * r;
        unsigned c  = cc + (cc >= r);
        int a  = (int)min(r, c);
        int bb = (int)max(r, c);
        int p  = (__umul24(a, 255 - a) >> 1) + bb - a - 1;   // pidx(a,bb)

        float sum = 0.0f;
        #pragma unroll
        for (int di = -1; di <= 0; ++di) {
            #pragma unroll
            for (int dj = -1; dj <= 0; ++dj) {
                int i = a + di, j = bb + dj;
                bool valid = (i >= 0) && (i <= 124) && (j >= i + 2) && (j <= 126);
                int s = valid ? (seg_row_base(i) + (j - i - 2)) : 0;
                float v = s_wr[s];
                sum += valid ? v : 0.0f;
            }
        }
        ob[k] = (p == 0 || p == PADLEN - 1) ? 0.0f : sum;
    }
}

extern "C" void kernel_launch(void* const* d_in, const int* in_sizes, int n_in,
                              void* d_out, int out_size, void* d_ws, size_t ws_size,
                              hipStream_t stream) {
    const float* xyz = (const float*)d_in[0];
    float*       out = (float*)d_out;

    int B = in_sizes[0] / (NATOMS * 3);   // 512 for the reference shapes

    // swr scratch: prefer d_ws; else pack into the tail of each batch's out
    // row (k2 stages to LDS before overwriting -- block-local, barrier-safe).
    size_t need = (size_t)B * NSEG * sizeof(float);
    float* swr;
    int    stride;
    if (ws_size >= need) {
        swr = (float*)d_ws;
        stride = NSEG;
    } else {
        swr = out + (OUT_PER_B - NSEG);   // offset 8381 within each row
        stride = OUT_PER_B;
    }

    writhe_k1<<<B * NBANDS, 256, 0, stream>>>(xyz, swr, stride);
    writhe_k2<<<B, 1024, 0, stream>>>(swr, stride, out);
}

// Round 8
// 102.159 us; speedup vs baseline: 1.1067x; 1.1067x over previous
//
#include <hip/hip_runtime.h>
#include <math.h>

#define NATOMS    128
#define NSEG      7875     // segments: i in [0,124], j in [i+2,126]
#define M_TRIU    8126     // (n*n-n)/2 - 2
#define PADLEN    8128     // M_TRIU + 2
#define OUT_PER_B 16256    // 2 * PADLEN
#define BLOCK     1024

struct F3 { float x, y, z; };
__device__ __forceinline__ F3 f3sub(F3 a, F3 b) { return {a.x - b.x, a.y - b.y, a.z - b.z}; }
__device__ __forceinline__ F3 f3cross(F3 a, F3 b) {
    return {a.y * b.z - a.z * b.y, a.z * b.x - a.x * b.z, a.x * b.y - a.y * b.x};
}
__device__ __forceinline__ float f3dot(F3 a, F3 b) { return a.x * b.x + a.y * b.y + a.z * b.z; }
__device__ __forceinline__ float clip1(float x) { return fminf(1.0f, fmaxf(-1.0f, x)); }

// Branchless asin, A&S 4.4.46 (|err| ~ 2e-8); single v_sqrt_f32.
__device__ __forceinline__ float fast_asin(float x) {
    float a = fabsf(x);
    float p = -0.0012624911f;
    p = fmaf(p, a,  0.0066700901f);
    p = fmaf(p, a, -0.0170881256f);
    p = fmaf(p, a,  0.0308918810f);
    p = fmaf(p, a, -0.0501743046f);
    p = fmaf(p, a,  0.0889789874f);
    p = fmaf(p, a, -0.2145988016f);
    p = fmaf(p, a,  1.5707963050f);
    float r = 1.57079632679f - __builtin_amdgcn_sqrtf(1.0f - a) * p;
    return copysignf(r, x);
}

__device__ __forceinline__ int seg_row_base(int i) { return 125 * i - (__umul24(i, i - 1) >> 1); }
__device__ __forceinline__ int pair_row_base(int a) { return (__umul24(a, 255 - a) >> 1); }

// Full writhe for segment s (clamped); reads coords from LDS SoA.
__device__ __forceinline__ float seg_writhe(int s, const float* sx, const float* sy,
                                            const float* sz) {
    int i = (int)((251.0f - __builtin_amdgcn_sqrtf(63001.0f - 8.0f * (float)s)) * 0.5f);
    i = max(i, 0);
    i += (seg_row_base(i + 1) <= s);
    i += (seg_row_base(i + 1) <= s);
    i -= (seg_row_base(i) > s);
    i -= (seg_row_base(i) > s);
    int j = s - seg_row_base(i) + i + 2;

    F3 p0 = {sx[i],     sy[i],     sz[i]};
    F3 p1 = {sx[i + 1], sy[i + 1], sz[i + 1]};
    F3 p2 = {sx[j],     sy[j],     sz[j]};
    F3 p3 = {sx[j + 1], sy[j + 1], sz[j + 1]};

    // Unnormalized displacements (scale cancels inside unit(cross)).
    F3 u0 = f3sub(p2, p0);
    F3 u1 = f3sub(p3, p0);
    F3 u2 = f3sub(p2, p1);
    F3 u3 = f3sub(p3, p1);

    F3 n0 = f3cross(u0, u1);
    F3 n1 = f3cross(u1, u3);
    F3 n2 = f3cross(u3, u2);
    F3 n3 = f3cross(u2, u0);

    float q0 = f3dot(n0, n0);
    float q1 = f3dot(n1, n1);
    float q2 = f3dot(n2, n2);
    float q3 = f3dot(n3, n3);

    float c0 = clip1(f3dot(n0, n1) * __builtin_amdgcn_rsqf(q0 * q1));
    float c1 = clip1(f3dot(n1, n2) * __builtin_amdgcn_rsqf(q1 * q2));
    float c2 = clip1(f3dot(n2, n3) * __builtin_amdgcn_rsqf(q2 * q3));
    float c3 = clip1(f3dot(n3, n0) * __builtin_amdgcn_rsqf(q3 * q0));

    F3 axial = f3cross(f3sub(p3, p2), f3sub(p1, p0));
    float sd = f3dot(axial, u0);
    float sgn = (sd > 0.0f) ? 1.0f : ((sd < 0.0f) ? -1.0f : 0.0f);

    float omega = fast_asin(c0) + fast_asin(c1) + fast_asin(c2) + fast_asin(c3);
    return omega * sgn * 0.15915494309189535f;  // / (2*pi)
}

// One block per batch. Phase A runs TWO independent segments per iteration
// (4 fixed iterations) so each wave always has two full dependency chains in
// flight. Phase C is the analytic inverse permutation (no sortv, verified in
// round 7): k -> (r,c) -> pair p; pads at p==0 / p==8127.
// LDS: coords 1.5K + swr 31.5K + triu 32.5K ~= 65.6 KB; 2 blocks/CU.
__global__ __launch_bounds__(BLOCK, 8) void writhe_fused(
    const float* __restrict__ xyz,       // (B, 128, 3)
    float*       __restrict__ out)       // (B, 16256)
{
    __shared__ float sx[NATOMS], sy[NATOMS], sz[NATOMS];
    __shared__ float swr[NSEG];
    __shared__ float triu[M_TRIU];

    const int b = blockIdx.x;
    const int t = threadIdx.x;

    if (t < 3 * NATOMS) {
        float v = xyz[(size_t)b * (3 * NATOMS) + t];
        int a = t / 3, c = t - 3 * a;
        if (c == 0) sx[a] = v; else if (c == 1) sy[a] = v; else sz[a] = v;
    }
    __syncthreads();

    // ---------- Phase A: writhe, 2-wide ILP ----------
    // 7875 = 7*1024 + 707. Pairs: (base+t, base+1024+t) for base = 0,2048,4096,6144.
    // All s0 are valid (max 7167); only the last s1 batch (7168..8191) needs a guard.
    #pragma unroll
    for (int base = 0; base < 8192; base += 2048) {
        int sA = base + t;
        int sB = sA + 1024;
        bool validB = (sB < NSEG);
        int sBc = validB ? sB : (NSEG - 1);
        float wA = seg_writhe(sA,  sx, sy, sz);
        float wB = seg_writhe(sBc, sx, sy, sz);
        swr[sA] = wA;
        if (validB) swr[sB] = wB;
    }
    __syncthreads();

    // ---------- Phase B: gather-form Laplacian into triu ----------
    for (int m = t; m < M_TRIU; m += BLOCK) {
        int q = m + 1;
        int a = (int)((255.0f - __builtin_amdgcn_sqrtf(65025.0f - 8.0f * (float)q)) * 0.5f);
        a = max(a, 0);
        a += (pair_row_base(a + 1) <= q);
        a += (pair_row_base(a + 1) <= q);
        a -= (pair_row_base(a) > q);
        a -= (pair_row_base(a) > q);
        int bb = a + 1 + (q - pair_row_base(a));

        float sum = 0.0f;
        #pragma unroll
        for (int di = -1; di <= 0; ++di) {
            #pragma unroll
            for (int dj = -1; dj <= 0; ++dj) {
                int i = a + di, j = bb + dj;
                bool valid = (i >= 0) && (i <= 124) && (j >= i + 2) && (j <= 126);
                int s = valid ? (seg_row_base(i) + (j - i - 2)) : 0;
                float v = swr[s];
                sum += valid ? v : 0.0f;
            }
        }
        triu[m] = sum;
    }
    __syncthreads();

    // ---------- Phase C: analytic permutation (no sortv) ----------
    float* ob = out + (size_t)b * OUT_PER_B;
    for (int k = t; k < OUT_PER_B; k += BLOCK) {
        unsigned r  = (unsigned)k / 127u;           // magic-mul
        unsigned cc = (unsigned)k - 127u * r;
        unsigned c  = cc + (cc >= r);
        int a  = (int)min(r, c);
        int bb = (int)max(r, c);
        int p  = pair_row_base(a) + bb - a - 1;     // pidx(a,bb)
        float val = (p == 0 || p == PADLEN - 1) ? 0.0f : triu[p - 1];
        ob[k] = val;
    }
}

extern "C" void kernel_launch(void* const* d_in, const int* in_sizes, int n_in,
                              void* d_out, int out_size, void* d_ws, size_t ws_size,
                              hipStream_t stream) {
    const float* xyz = (const float*)d_in[0];
    float*       out = (float*)d_out;

    int B = in_sizes[0] / (NATOMS * 3);   // 512 for the reference shapes
    writhe_fused<<<B, BLOCK, 0, stream>>>(xyz, out);
}

// Round 9
// 97.318 us; speedup vs baseline: 1.1618x; 1.0497x over previous
//
#include <hip/hip_runtime.h>
#include <math.h>

#define NATOMS    128
#define NSEG      7875     // segments: i in [0,124], j in [i+2,126]
#define M_TRIU    8126     // (n*n-n)/2 - 2
#define PADLEN    8128     // M_TRIU + 2
#define OUT_PER_B 16256    // 2 * PADLEN
#define BLOCK     1024

struct F3 { float x, y, z; };
__device__ __forceinline__ F3 f3sub(F3 a, F3 b) { return {a.x - b.x, a.y - b.y, a.z - b.z}; }
__device__ __forceinline__ F3 f3cross(F3 a, F3 b) {
    return {a.y * b.z - a.z * b.y, a.z * b.x - a.x * b.z, a.x * b.y - a.y * b.x};
}
__device__ __forceinline__ float f3dot(F3 a, F3 b) { return a.x * b.x + a.y * b.y + a.z * b.z; }
__device__ __forceinline__ float clip1(float x) { return fminf(1.0f, fmaxf(-1.0f, x)); }

// 4-term branchless asin, A&S 4.4.45 (|err| <= 6.8e-5 -- threshold is 5.9e-2).
__device__ __forceinline__ float fast_asin(float x) {
    float a = fabsf(x);
    float p = -0.0187293f;
    p = fmaf(p, a,  0.0742610f);
    p = fmaf(p, a, -0.2121144f);
    p = fmaf(p, a,  1.5707288f);
    float r = 1.57079632679f - __builtin_amdgcn_sqrtf(1.0f - a) * p;
    return copysignf(r, x);
}

__device__ __forceinline__ int seg_row_base(int i) { return 125 * i - (__umul24(i, i - 1) >> 1); }
__device__ __forceinline__ int pair_row_base(int a) { return (__umul24(a, 255 - a) >> 1); }

// Writhe for a packed segment (i<<7)|j; coords from LDS SoA.
__device__ __forceinline__ float seg_writhe_packed(unsigned pack, const float* sx,
                                                   const float* sy, const float* sz) {
    int j = (int)(pack & 127u);
    int i = (int)(pack >> 7);

    F3 p0 = {sx[i],     sy[i],     sz[i]};
    F3 p1 = {sx[i + 1], sy[i + 1], sz[i + 1]};
    F3 p2 = {sx[j],     sy[j],     sz[j]};
    F3 p3 = {sx[j + 1], sy[j + 1], sz[j + 1]};

    // Unnormalized displacements (scale cancels inside unit(cross)).
    F3 u0 = f3sub(p2, p0);
    F3 u1 = f3sub(p3, p0);
    F3 u2 = f3sub(p2, p1);
    F3 u3 = f3sub(p3, p1);

    F3 n0 = f3cross(u0, u1);
    F3 n1 = f3cross(u1, u3);
    F3 n2 = f3cross(u3, u2);
    F3 n3 = f3cross(u2, u0);

    float q0 = f3dot(n0, n0);
    float q1 = f3dot(n1, n1);
    float q2 = f3dot(n2, n2);
    float q3 = f3dot(n3, n3);

    float c0 = clip1(f3dot(n0, n1) * __builtin_amdgcn_rsqf(q0 * q1));
    float c1 = clip1(f3dot(n1, n2) * __builtin_amdgcn_rsqf(q1 * q2));
    float c2 = clip1(f3dot(n2, n3) * __builtin_amdgcn_rsqf(q2 * q3));
    float c3 = clip1(f3dot(n3, n0) * __builtin_amdgcn_rsqf(q3 * q0));

    F3 axial = f3cross(f3sub(p3, p2), f3sub(p1, p0));
    float sd = f3dot(axial, u0);
    float sgn = (sd > 0.0f) ? 1.0f : ((sd < 0.0f) ? -1.0f : 0.0f);

    float omega = fast_asin(c0) + fast_asin(c1) + fast_asin(c2) + fast_asin(c3);
    return omega * sgn * 0.15915494309189535f;  // / (2*pi)
}

// One block per batch. sidx[] (u16 packed (i,j) per segment, built once per
// block by a sequential 8-step walk) replaces the ~45-op per-segment index
// inversion; it is overlaid on triu (dead until Phase B; barrier-separated).
// Phase A keeps the 2-wide ILP pairing; Phase C is analytic (no sortv).
// LDS: coords 1.5K + swr 31.5K + triu/sidx 32.5K ~= 65.5 KB; 2 blocks/CU.
__global__ __launch_bounds__(BLOCK, 8) void writhe_fused(
    const float* __restrict__ xyz,       // (B, 128, 3)
    float*       __restrict__ out)       // (B, 16256)
{
    __shared__ float sx[NATOMS], sy[NATOMS], sz[NATOMS];
    __shared__ float swr[NSEG];
    __shared__ float triu[M_TRIU];
    unsigned short* sidx = (unsigned short*)triu;   // overlay: dead before Phase B

    const int b = blockIdx.x;
    const int t = threadIdx.x;

    if (t < 3 * NATOMS) {
        float v = xyz[(size_t)b * (3 * NATOMS) + t];
        int a = t / 3, c = t - 3 * a;
        if (c == 0) sx[a] = v; else if (c == 1) sy[a] = v; else sz[a] = v;
    }

    // ---------- Phase 0: build sidx (one inversion + cheap 8-step walk) ----------
    {
        int s = t * 8;
        if (s < NSEG) {
            int i = (int)((251.0f - __builtin_amdgcn_sqrtf(63001.0f - 8.0f * (float)s)) * 0.5f);
            i = max(i, 0);
            i += (seg_row_base(i + 1) <= s);
            i += (seg_row_base(i + 1) <= s);
            i -= (seg_row_base(i) > s);
            i -= (seg_row_base(i) > s);
            int j = s - seg_row_base(i) + i + 2;
            #pragma unroll
            for (int k = 0; k < 8; ++k) {
                if (s < NSEG) sidx[s] = (unsigned short)((i << 7) | j);
                ++s; ++j;
                if (j > 126) { ++i; j = i + 2; }
            }
        }
    }
    __syncthreads();

    // ---------- Phase A: writhe, 2-wide ILP ----------
    #pragma unroll
    for (int base = 0; base < 8192; base += 2048) {
        int sA = base + t;              // always < 7168, valid
        int sB = sA + 1024;
        bool validB = (sB < NSEG);
        int sBc = validB ? sB : (NSEG - 1);
        unsigned pA = sidx[sA];
        unsigned pB = sidx[sBc];
        float wA = seg_writhe_packed(pA, sx, sy, sz);
        float wB = seg_writhe_packed(pB, sx, sy, sz);
        swr[sA] = wA;
        if (validB) swr[sB] = wB;
    }
    __syncthreads();   // sidx dead past this point; triu may be written

    // ---------- Phase B: gather-form Laplacian into triu ----------
    for (int m = t; m < M_TRIU; m += BLOCK) {
        int q = m + 1;
        int a = (int)((255.0f - __builtin_amdgcn_sqrtf(65025.0f - 8.0f * (float)q)) * 0.5f);
        a = max(a, 0);
        a += (pair_row_base(a + 1) <= q);
        a += (pair_row_base(a + 1) <= q);
        a -= (pair_row_base(a) > q);
        a -= (pair_row_base(a) > q);
        int bb = a + 1 + (q - pair_row_base(a));

        float sum = 0.0f;
        #pragma unroll
        for (int di = -1; di <= 0; ++di) {
            #pragma unroll
            for (int dj = -1; dj <= 0; ++dj) {
                int i = a + di, j = bb + dj;
                bool valid = (i >= 0) && (i <= 124) && (j >= i + 2) && (j <= 126);
                int s = valid ? (seg_row_base(i) + (j - i - 2)) : 0;
                float v = swr[s];
                sum += valid ? v : 0.0f;
            }
        }
        triu[m] = sum;
    }
    __syncthreads();

    // ---------- Phase C: analytic permutation (no sortv) ----------
    float* ob = out + (size_t)b * OUT_PER_B;
    for (int k = t; k < OUT_PER_B; k += BLOCK) {
        unsigned r  = (unsigned)k / 127u;           // magic-mul
        unsigned cc = (unsigned)k - 127u * r;
        unsigned c  = cc + (cc >= r);
        int a  = (int)min(r, c);
        int bb = (int)max(r, c);
        int p  = pair_row_base(a) + bb - a - 1;     // pidx(a,bb)
        float val = (p == 0 || p == PADLEN - 1) ? 0.0f : triu[p - 1];
        ob[k] = val;
    }
}

extern "C" void kernel_launch(void* const* d_in, const int* in_sizes, int n_in,
                              void* d_out, int out_size, void* d_ws, size_t ws_size,
                              hipStream_t stream) {
    const float* xyz = (const float*)d_in[0];
    float*       out = (float*)d_out;

    int B = in_sizes[0] / (NATOMS * 3);   // 512 for the reference shapes
    writhe_fused<<<B, BLOCK, 0, stream>>>(xyz, out);
}

// Round 10
// 96.596 us; speedup vs baseline: 1.1705x; 1.0075x over previous
//
#include <hip/hip_runtime.h>
#include <math.h>

#define NATOMS    128
#define NSEG      7875     // segments: i in [0,124], j in [i+2,126]
#define M_TRIU    8126     // (n*n-n)/2 - 2
#define PADLEN    8128     // M_TRIU + 2
#define OUT_PER_B 16256    // 2 * PADLEN
#define BLOCK     1024

struct F3 { float x, y, z; };
__device__ __forceinline__ F3 f3sub(F3 a, F3 b) { return {a.x - b.x, a.y - b.y, a.z - b.z}; }
__device__ __forceinline__ F3 f3cross(F3 a, F3 b) {
    return {a.y * b.z - a.z * b.y, a.z * b.x - a.x * b.z, a.x * b.y - a.y * b.x};
}
__device__ __forceinline__ float f3dot(F3 a, F3 b) { return a.x * b.x + a.y * b.y + a.z * b.z; }
__device__ __forceinline__ float clip1(float x) { return fminf(1.0f, fmaxf(-1.0f, x)); }

// 4-term branchless asin, A&S 4.4.45 (|err| <= 6.8e-5 -- threshold is 5.9e-2).
__device__ __forceinline__ float fast_asin(float x) {
    float a = fabsf(x);
    float p = -0.0187293f;
    p = fmaf(p, a,  0.0742610f);
    p = fmaf(p, a, -0.2121144f);
    p = fmaf(p, a,  1.5707288f);
    float r = 1.57079632679f - __builtin_amdgcn_sqrtf(1.0f - a) * p;
    return copysignf(r, x);
}

__device__ __forceinline__ int seg_row_base(int i) { return 125 * i - (__umul24(i, i - 1) >> 1); }
__device__ __forceinline__ int pair_row_base(int a) { return (__umul24(a, 255 - a) >> 1); }

// Writhe for a packed segment (i<<7)|j; coords from LDS SoA.
// Points die immediately after the u-subs: axial = cross(u3-u2, u0-u2)
// since p3-p2 == u3-u2 and p1-p0 == u0-u2 (keeps live set ~small for 4-wide).
__device__ __forceinline__ float seg_writhe_packed(unsigned pack, const float* sx,
                                                   const float* sy, const float* sz) {
    int j = (int)(pack & 127u);
    int i = (int)(pack >> 7);

    F3 p0 = {sx[i],     sy[i],     sz[i]};
    F3 p1 = {sx[i + 1], sy[i + 1], sz[i + 1]};
    F3 p2 = {sx[j],     sy[j],     sz[j]};
    F3 p3 = {sx[j + 1], sy[j + 1], sz[j + 1]};

    // Unnormalized displacements (scale cancels inside unit(cross)).
    F3 u0 = f3sub(p2, p0);
    F3 u1 = f3sub(p3, p0);
    F3 u2 = f3sub(p2, p1);
    F3 u3 = f3sub(p3, p1);

    F3 n0 = f3cross(u0, u1);
    F3 n1 = f3cross(u1, u3);
    F3 n2 = f3cross(u3, u2);
    F3 n3 = f3cross(u2, u0);

    F3 axial = f3cross(f3sub(u3, u2), f3sub(u0, u2));
    float sd = f3dot(axial, u0);
    float sgn = (sd > 0.0f) ? 1.0f : ((sd < 0.0f) ? -1.0f : 0.0f);

    float q0 = f3dot(n0, n0);
    float q1 = f3dot(n1, n1);
    float q2 = f3dot(n2, n2);
    float q3 = f3dot(n3, n3);

    float c0 = clip1(f3dot(n0, n1) * __builtin_amdgcn_rsqf(q0 * q1));
    float c1 = clip1(f3dot(n1, n2) * __builtin_amdgcn_rsqf(q1 * q2));
    float c2 = clip1(f3dot(n2, n3) * __builtin_amdgcn_rsqf(q2 * q3));
    float c3 = clip1(f3dot(n3, n0) * __builtin_amdgcn_rsqf(q3 * q0));

    float omega = fast_asin(c0) + fast_asin(c1) + fast_asin(c2) + fast_asin(c3);
    return omega * sgn * 0.15915494309189535f;  // / (2*pi)
}

// One block per batch. sidx[] (u16 packed (i,j), built once per block) is
// overlaid on triu (dead until Phase B; barrier-separated). Phase A runs
// FOUR independent segment chains per iteration (2 iterations); Phase C is
// the analytic inverse permutation (no sortv).
// LDS: coords 1.5K + swr 31.5K + triu/sidx 32.5K ~= 65.5 KB; 2 blocks/CU.
__global__ __launch_bounds__(BLOCK, 8) void writhe_fused(
    const float* __restrict__ xyz,       // (B, 128, 3)
    float*       __restrict__ out)       // (B, 16256)
{
    __shared__ float sx[NATOMS], sy[NATOMS], sz[NATOMS];
    __shared__ float swr[NSEG];
    __shared__ float triu[M_TRIU];
    unsigned short* sidx = (unsigned short*)triu;   // overlay: dead before Phase B

    const int b = blockIdx.x;
    const int t = threadIdx.x;

    if (t < 3 * NATOMS) {
        float v = xyz[(size_t)b * (3 * NATOMS) + t];
        int a = t / 3, c = t - 3 * a;
        if (c == 0) sx[a] = v; else if (c == 1) sy[a] = v; else sz[a] = v;
    }

    // ---------- Phase 0: build sidx (one inversion + cheap 8-step walk) ----------
    {
        int s = t * 8;
        if (s < NSEG) {
            int i = (int)((251.0f - __builtin_amdgcn_sqrtf(63001.0f - 8.0f * (float)s)) * 0.5f);
            i = max(i, 0);
            i += (seg_row_base(i + 1) <= s);
            i += (seg_row_base(i + 1) <= s);
            i -= (seg_row_base(i) > s);
            i -= (seg_row_base(i) > s);
            int j = s - seg_row_base(i) + i + 2;
            #pragma unroll
            for (int k = 0; k < 8; ++k) {
                if (s < NSEG) sidx[s] = (unsigned short)((i << 7) | j);
                ++s; ++j;
                if (j > 126) { ++i; j = i + 2; }
            }
        }
    }
    __syncthreads();

    // ---------- Phase A: writhe, 4-wide ILP x 2 iterations ----------
    #pragma unroll
    for (int half = 0; half < 2; ++half) {
        const int s0 = half * 4096 + t;
        unsigned pk[4];
        bool     vl[4];
        #pragma unroll
        for (int k = 0; k < 4; ++k) {
            int s = s0 + k * 1024;
            vl[k] = (s < NSEG);
            pk[k] = sidx[vl[k] ? s : (NSEG - 1)];
        }
        float w[4];
        #pragma unroll
        for (int k = 0; k < 4; ++k)
            w[k] = seg_writhe_packed(pk[k], sx, sy, sz);
        #pragma unroll
        for (int k = 0; k < 4; ++k)
            if (vl[k]) swr[s0 + k * 1024] = w[k];
    }
    __syncthreads();   // sidx dead past this point; triu may be written

    // ---------- Phase B: gather-form Laplacian into triu ----------
    for (int m = t; m < M_TRIU; m += BLOCK) {
        int q = m + 1;
        int a = (int)((255.0f - __builtin_amdgcn_sqrtf(65025.0f - 8.0f * (float)q)) * 0.5f);
        a = max(a, 0);
        a += (pair_row_base(a + 1) <= q);
        a += (pair_row_base(a + 1) <= q);
        a -= (pair_row_base(a) > q);
        a -= (pair_row_base(a) > q);
        int bb = a + 1 + (q - pair_row_base(a));

        float sum = 0.0f;
        #pragma unroll
        for (int di = -1; di <= 0; ++di) {
            #pragma unroll
            for (int dj = -1; dj <= 0; ++dj) {
                int i = a + di, j = bb + dj;
                bool valid = (i >= 0) && (i <= 124) && (j >= i + 2) && (j <= 126);
                int s = valid ? (seg_row_base(i) + (j - i - 2)) : 0;
                float v = swr[s];
                sum += valid ? v : 0.0f;
            }
        }
        triu[m] = sum;
    }
    __syncthreads();

    // ---------- Phase C: analytic permutation (no sortv) ----------
    float* ob = out + (size_t)b * OUT_PER_B;
    for (int k = t; k < OUT_PER_B; k += BLOCK) {
        unsigned r  = (unsigned)k / 127u;           // magic-mul
        unsigned cc = (unsigned)k - 127u * r;
        unsigned c  = cc + (cc >= r);
        int a  = (int)min(r, c);
        int bb = (int)max(r, c);
        int p  = pair_row_base(a) + bb - a - 1;     // pidx(a,bb)
        float val = (p == 0 || p == PADLEN - 1) ? 0.0f : triu[p - 1];
        ob[k] = val;
    }
}

extern "C" void kernel_launch(void* const* d_in, const int* in_sizes, int n_in,
                              void* d_out, int out_size, void* d_ws, size_t ws_size,
                              hipStream_t stream) {
    const float* xyz = (const float*)d_in[0];
    float*       out = (float*)d_out;

    int B = in_sizes[0] / (NATOMS * 3);   // 512 for the reference shapes
    writhe_fused<<<B, BLOCK, 0, stream>>>(xyz, out);
}

// Round 11
// 95.730 us; speedup vs baseline: 1.1811x; 1.0090x over previous
//
#include <hip/hip_runtime.h>
#include <math.h>

#define NATOMS    128
#define NSEG      7875     // segments: i in [0,124], j in [i+2,126]
#define NPAIR     8128     // pairs (a,b), 0 <= a < b <= 127
#define OUT_PER_B 16256    // 128*127 (row-major, diagonal skipped)
#define BLOCK     1024

struct F3 { float x, y, z; };
__device__ __forceinline__ F3 f3sub(F3 a, F3 b) { return {a.x - b.x, a.y - b.y, a.z - b.z}; }
__device__ __forceinline__ F3 f3cross(F3 a, F3 b) {
    return {a.y * b.z - a.z * b.y, a.z * b.x - a.x * b.z, a.x * b.y - a.y * b.x};
}
__device__ __forceinline__ float f3dot(F3 a, F3 b) { return a.x * b.x + a.y * b.y + a.z * b.z; }
__device__ __forceinline__ float clip1(float x) { return fminf(1.0f, fmaxf(-1.0f, x)); }

// 4-term branchless asin, A&S 4.4.45 (|err| <= 6.8e-5 -- threshold is 5.9e-2).
__device__ __forceinline__ float fast_asin(float x) {
    float a = fabsf(x);
    float p = -0.0187293f;
    p = fmaf(p, a,  0.0742610f);
    p = fmaf(p, a, -0.2121144f);
    p = fmaf(p, a,  1.5707288f);
    float r = 1.57079632679f - __builtin_amdgcn_sqrtf(1.0f - a) * p;
    return copysignf(r, x);
}

__device__ __forceinline__ int seg_row_base(int i) { return 125 * i - (__umul24(i, i - 1) >> 1); }
__device__ __forceinline__ int pair_row_base(int a) { return (__umul24(a, 255 - a) >> 1); }

// Writhe for a packed segment (i<<7)|j; coords from LDS SoA.
__device__ __forceinline__ float seg_writhe_packed(unsigned pack, const float* sx,
                                                   const float* sy, const float* sz) {
    int j = (int)(pack & 127u);
    int i = (int)(pack >> 7);

    F3 p0 = {sx[i],     sy[i],     sz[i]};
    F3 p1 = {sx[i + 1], sy[i + 1], sz[i + 1]};
    F3 p2 = {sx[j],     sy[j],     sz[j]};
    F3 p3 = {sx[j + 1], sy[j + 1], sz[j + 1]};

    // Unnormalized displacements (scale cancels inside unit(cross)).
    F3 u0 = f3sub(p2, p0);
    F3 u1 = f3sub(p3, p0);
    F3 u2 = f3sub(p2, p1);
    F3 u3 = f3sub(p3, p1);

    F3 n0 = f3cross(u0, u1);
    F3 n1 = f3cross(u1, u3);
    F3 n2 = f3cross(u3, u2);
    F3 n3 = f3cross(u2, u0);

    F3 axial = f3cross(f3sub(u3, u2), f3sub(u0, u2));   // == cross(p3-p2, p1-p0)
    float sd = f3dot(axial, u0);
    float sgn = (sd > 0.0f) ? 1.0f : ((sd < 0.0f) ? -1.0f : 0.0f);

    float q0 = f3dot(n0, n0);
    float q1 = f3dot(n1, n1);
    float q2 = f3dot(n2, n2);
    float q3 = f3dot(n3, n3);

    float c0 = clip1(f3dot(n0, n1) * __builtin_amdgcn_rsqf(q0 * q1));
    float c1 = clip1(f3dot(n1, n2) * __builtin_amdgcn_rsqf(q1 * q2));
    float c2 = clip1(f3dot(n2, n3) * __builtin_amdgcn_rsqf(q2 * q3));
    float c3 = clip1(f3dot(n3, n0) * __builtin_amdgcn_rsqf(q3 * q0));

    float omega = fast_asin(c0) + fast_asin(c1) + fast_asin(c2) + fast_asin(c3);
    return omega * sgn * 0.15915494309189535f;  // / (2*pi)
}

// One block per batch.
// Phase 0: build u16 index tables (sidx: segment->(i,j); spair: pair->(a,b)).
// Phase A: writhe -> swr, 4-wide ILP.
// Phase D: per PAIR (a,b): gather its <=4 segments from swr, write the sum to
//   BOTH output slots k1 = 127a+b-1 (r<c, coalesced) and k2 = 127b+a (r>c,
//   stride-127; output is L3-resident so partial lines merge). This replaces
//   the old triu build (Phase B) + permuted read-out (Phase C) and removes a
//   barrier, the triu LDS array, and the k->(r,c) division.
//   Natural zero at the pads: pairs (0,1) and (126,127) have no valid segment.
// LDS: coords 1.5K + swr 31.5K + sidx 15.75K + spair 16.25K ~= 65 KB; 2 blocks/CU.
__global__ __launch_bounds__(BLOCK, 8) void writhe_fused(
    const float* __restrict__ xyz,       // (B, 128, 3)
    float*       __restrict__ out)       // (B, 16256)
{
    __shared__ float sx[NATOMS], sy[NATOMS], sz[NATOMS];
    __shared__ float swr[NSEG];
    __shared__ unsigned short sidx[NSEG];
    __shared__ unsigned short spair[NPAIR];

    const int b = blockIdx.x;
    const int t = threadIdx.x;

    if (t < 3 * NATOMS) {
        float v = xyz[(size_t)b * (3 * NATOMS) + t];
        int a = t / 3, c = t - 3 * a;
        if (c == 0) sx[a] = v; else if (c == 1) sy[a] = v; else sz[a] = v;
    }

    // ---------- Phase 0a: build sidx ----------
    {
        int s = t * 8;
        if (s < NSEG) {
            int i = (int)((251.0f - __builtin_amdgcn_sqrtf(63001.0f - 8.0f * (float)s)) * 0.5f);
            i = max(i, 0);
            i += (seg_row_base(i + 1) <= s);
            i += (seg_row_base(i + 1) <= s);
            i -= (seg_row_base(i) > s);
            i -= (seg_row_base(i) > s);
            int j = s - seg_row_base(i) + i + 2;
            #pragma unroll
            for (int k = 0; k < 8; ++k) {
                if (s < NSEG) sidx[s] = (unsigned short)((i << 7) | j);
                ++s; ++j;
                if (j > 126) { ++i; j = i + 2; }
            }
        }
    }
    // ---------- Phase 0b: build spair ----------
    {
        int p = t * 8;
        if (p < NPAIR) {
            int a = (int)((255.0f - __builtin_amdgcn_sqrtf(65025.0f - 8.0f * (float)p)) * 0.5f);
            a = max(a, 0);
            a += (pair_row_base(a + 1) <= p);
            a += (pair_row_base(a + 1) <= p);
            a -= (pair_row_base(a) > p);
            a -= (pair_row_base(a) > p);
            int bb = a + 1 + (p - pair_row_base(a));
            #pragma unroll
            for (int k = 0; k < 8; ++k) {
                if (p < NPAIR) spair[p] = (unsigned short)((a << 7) | bb);
                ++p; ++bb;
                if (bb > 127) { ++a; bb = a + 1; }
            }
        }
    }
    __syncthreads();

    // ---------- Phase A: writhe, 4-wide ILP x 2 iterations ----------
    #pragma unroll
    for (int half = 0; half < 2; ++half) {
        const int s0 = half * 4096 + t;
        unsigned pk[4];
        bool     vl[4];
        #pragma unroll
        for (int k = 0; k < 4; ++k) {
            int s = s0 + k * 1024;
            vl[k] = (s < NSEG);
            pk[k] = sidx[vl[k] ? s : (NSEG - 1)];
        }
        float w[4];
        #pragma unroll
        for (int k = 0; k < 4; ++k)
            w[k] = seg_writhe_packed(pk[k], sx, sy, sz);
        #pragma unroll
        for (int k = 0; k < 4; ++k)
            if (vl[k]) swr[s0 + k * 1024] = w[k];
    }
    __syncthreads();

    // ---------- Phase D: per-pair gather + dual store ----------
    float* ob = out + (size_t)b * OUT_PER_B;
    for (int p = t; p < NPAIR; p += BLOCK) {
        unsigned pk = spair[p];
        int bb = (int)(pk & 127u);
        int a  = (int)(pk >> 7);

        // segment ids for (i,j) in {a-1,a} x {b-1,b}; s(i,j)=base(i)+j-i-2
        int am1 = a - 1;
        int s00 = 125 * am1 - ((am1 * (am1 - 1)) >> 1) + bb - a - 2;  // (a-1, b-1)
        int s10 = s00 + 125 - a;                                      // (a,   b-1)

        bool v00 = (a >= 1) && (a <= 125) && (bb >= a + 2);
        bool v01 = (a >= 1) && (a <= 125) && (bb <= 126);
        bool v10 = (a <= 124) && (bb >= a + 3);
        bool v11 = (a <= 124) && (bb <= 126) && (bb >= a + 2);

        int c00 = min(max(s00,     0), NSEG - 1);
        int c01 = min(max(s00 + 1, 0), NSEG - 1);
        int c10 = min(max(s10,     0), NSEG - 1);
        int c11 = min(max(s10 + 1, 0), NSEG - 1);

        float sum = (v00 ? swr[c00] : 0.0f) + (v01 ? swr[c01] : 0.0f)
                  + (v10 ? swr[c10] : 0.0f) + (v11 ? swr[c11] : 0.0f);

        int k1 = 127 * a + bb - 1;   // (r,c) = (a,b), r < c
        int k2 = 127 * bb + a;       // (r,c) = (b,a), r > c
        ob[k1] = sum;
        ob[k2] = sum;
    }
}

extern "C" void kernel_launch(void* const* d_in, const int* in_sizes, int n_in,
                              void* d_out, int out_size, void* d_ws, size_t ws_size,
                              hipStream_t stream) {
    const float* xyz = (const float*)d_in[0];
    float*       out = (float*)d_out;

    int B = in_sizes[0] / (NATOMS * 3);   // 512 for the reference shapes
    writhe_fused<<<B, BLOCK, 0, stream>>>(xyz, out);
}

// Round 12
// 92.753 us; speedup vs baseline: 1.2190x; 1.0321x over previous
//
#include <hip/hip_runtime.h>
#include <math.h>

#define NATOMS    128
#define NSEG      7875     // segments: i in [0,124], j in [i+2,126]
#define NSEG_PAD  8192     // padded so Phase A needs no predication
#define NPAIR     8128     // pairs (a,b), 0 <= a < b <= 127
#define OUT_PER_B 16256    // 128*127 (row-major, diagonal skipped)
#define BLOCK     1024

typedef float v2f __attribute__((ext_vector_type(2)));
__device__ __forceinline__ v2f mk2(float a, float b) { v2f r; r.x = a; r.y = b; return r; }

struct P3 { v2f x, y, z; };
__device__ __forceinline__ P3 psub(P3 a, P3 b) { return {a.x - b.x, a.y - b.y, a.z - b.z}; }
__device__ __forceinline__ P3 pcross(P3 a, P3 b) {
    return {a.y * b.z - a.z * b.y, a.z * b.x - a.x * b.z, a.x * b.y - a.y * b.x};
}
__device__ __forceinline__ v2f pdot(P3 a, P3 b) { return a.x * b.x + a.y * b.y + a.z * b.z; }
__device__ __forceinline__ v2f prsq(v2f q) {
    v2f r; r.x = __builtin_amdgcn_rsqf(q.x); r.y = __builtin_amdgcn_rsqf(q.y); return r;
}
__device__ __forceinline__ v2f pclip1(v2f x) {
    return __builtin_elementwise_min(__builtin_elementwise_max(x, mk2(-1.f, -1.f)),
                                     mk2(1.f, 1.f));
}

// Packed 4-term branchless asin, A&S 4.4.45 (|err| <= 6.8e-5; threshold 5.9e-2).
__device__ __forceinline__ v2f fast_asin2(v2f x) {
    v2f a = __builtin_elementwise_abs(x);
    v2f p = mk2(-0.0187293f, -0.0187293f);
    p = p * a + mk2( 0.0742610f,  0.0742610f);
    p = p * a + mk2(-0.2121144f, -0.2121144f);
    p = p * a + mk2( 1.5707288f,  1.5707288f);
    v2f om = mk2(1.0f, 1.0f) - a;
    v2f sq; sq.x = __builtin_amdgcn_sqrtf(om.x); sq.y = __builtin_amdgcn_sqrtf(om.y);
    v2f r = mk2(1.57079632679f, 1.57079632679f) - sq * p;
    return __builtin_elementwise_copysign(r, x);
}

__device__ __forceinline__ int seg_row_base(int i) { return 125 * i - (__umul24(i, i - 1) >> 1); }
__device__ __forceinline__ int pair_row_base(int a) { return (__umul24(a, 255 - a) >> 1); }

// Writhe for TWO packed segments (x-lane = pa, y-lane = pb), all 3D math in
// packed f32 (v_pk_*). Sign via the exact identity
//   cross(p3-p2, p1-p0) . u0 = -(u3 x u2) . u0 = -n2 . u0
// (expand (u3-u2)x(u0-u2).u0; the u0- and u2-triple products vanish), which
// deletes the axial cross entirely.
__device__ __forceinline__ v2f seg_writhe_pair(unsigned pa, unsigned pb,
                                               const float* sx, const float* sy,
                                               const float* sz) {
    int jA = (int)(pa & 127u), iA = (int)(pa >> 7);
    int jB = (int)(pb & 127u), iB = (int)(pb >> 7);

    P3 p0 = {mk2(sx[iA],     sx[iB]),     mk2(sy[iA],     sy[iB]),     mk2(sz[iA],     sz[iB])};
    P3 p1 = {mk2(sx[iA + 1], sx[iB + 1]), mk2(sy[iA + 1], sy[iB + 1]), mk2(sz[iA + 1], sz[iB + 1])};
    P3 p2 = {mk2(sx[jA],     sx[jB]),     mk2(sy[jA],     sy[jB]),     mk2(sz[jA],     sz[jB])};
    P3 p3 = {mk2(sx[jA + 1], sx[jB + 1]), mk2(sy[jA + 1], sy[jB + 1]), mk2(sz[jA + 1], sz[jB + 1])};

    P3 u0 = psub(p2, p0);
    P3 u1 = psub(p3, p0);
    P3 u2 = psub(p2, p1);
    P3 u3 = psub(p3, p1);

    P3 n0 = pcross(u0, u1);
    P3 n1 = pcross(u1, u3);
    P3 n2 = pcross(u3, u2);
    P3 n3 = pcross(u2, u0);

    v2f q0 = pdot(n0, n0);
    v2f q1 = pdot(n1, n1);
    v2f q2 = pdot(n2, n2);
    v2f q3 = pdot(n3, n3);

    v2f c0 = pclip1(pdot(n0, n1) * prsq(q0 * q1));
    v2f c1 = pclip1(pdot(n1, n2) * prsq(q1 * q2));
    v2f c2 = pclip1(pdot(n2, n3) * prsq(q2 * q3));
    v2f c3 = pclip1(pdot(n3, n0) * prsq(q3 * q0));

    v2f sd = pdot(n2, u0);     // = -(reference sd); sign folded below
    v2f omega = fast_asin2(c0) + fast_asin2(c1) + fast_asin2(c2) + fast_asin2(c3);

    v2f sgn;
    sgn.x = (sd.x > 0.f) ? -1.f : ((sd.x < 0.f) ? 1.f : 0.f);
    sgn.y = (sd.y > 0.f) ? -1.f : ((sd.y < 0.f) ? 1.f : 0.f);

    return omega * sgn * mk2(0.15915494309189535f, 0.15915494309189535f);
}

// One block per batch.
// Phase 0: u16 index tables (sidx padded to 8192; spair).
// Phase A: packed-pair writhe -> swr (padded, unconditional), 2 independent
//          packed chains per iteration x 2 iterations = 8 segments/thread.
// Phase D: per-pair gather from swr + dual store (verified round 11).
// LDS: coords 1.5K + swr 32K + sidx 16K + spair 16.25K ~= 65.4 KB; 2 blocks/CU.
__global__ __launch_bounds__(BLOCK, 8) void writhe_fused(
    const float* __restrict__ xyz,       // (B, 128, 3)
    float*       __restrict__ out)       // (B, 16256)
{
    __shared__ float sx[NATOMS], sy[NATOMS], sz[NATOMS];
    __shared__ float swr[NSEG_PAD];
    __shared__ unsigned short sidx[NSEG_PAD];
    __shared__ unsigned short spair[NPAIR];

    const int b = blockIdx.x;
    const int t = threadIdx.x;

    if (t < 3 * NATOMS) {
        float v = xyz[(size_t)b * (3 * NATOMS) + t];
        int a = t / 3, c = t - 3 * a;
        if (c == 0) sx[a] = v; else if (c == 1) sy[a] = v; else sz[a] = v;
    }

    // ---------- Phase 0a: build sidx (+ pad tail with a safe segment) ----------
    {
        int s = t * 8;
        if (s < NSEG) {
            int i = (int)((251.0f - __builtin_amdgcn_sqrtf(63001.0f - 8.0f * (float)s)) * 0.5f);
            i = max(i, 0);
            i += (seg_row_base(i + 1) <= s);
            i += (seg_row_base(i + 1) <= s);
            i -= (seg_row_base(i) > s);
            i -= (seg_row_base(i) > s);
            int j = s - seg_row_base(i) + i + 2;
            #pragma unroll
            for (int k = 0; k < 8; ++k) {
                if (s < NSEG) sidx[s] = (unsigned short)((i << 7) | j);
                ++s; ++j;
                if (j > 126) { ++i; j = i + 2; }
            }
        }
        if (t < NSEG_PAD - NSEG) sidx[NSEG + t] = (unsigned short)((124 << 7) | 126);
    }
    // ---------- Phase 0b: build spair ----------
    {
        int p = t * 8;
        if (p < NPAIR) {
            int a = (int)((255.0f - __builtin_amdgcn_sqrtf(65025.0f - 8.0f * (float)p)) * 0.5f);
            a = max(a, 0);
            a += (pair_row_base(a + 1) <= p);
            a += (pair_row_base(a + 1) <= p);
            a -= (pair_row_base(a) > p);
            a -= (pair_row_base(a) > p);
            int bb = a + 1 + (p - pair_row_base(a));
            #pragma unroll
            for (int k = 0; k < 8; ++k) {
                if (p < NPAIR) spair[p] = (unsigned short)((a << 7) | bb);
                ++p; ++bb;
                if (bb > 127) { ++a; bb = a + 1; }
            }
        }
    }
    __syncthreads();

    // ---------- Phase A: packed-pair writhe, 2 chains x 2 iterations ----------
    #pragma unroll
    for (int g = 0; g < 2; ++g) {
        const int sA = g * 4096 + t;     // all of sA..sA+3072 < 8192: unconditional
        v2f w1 = seg_writhe_pair(sidx[sA],        sidx[sA + 1024], sx, sy, sz);
        v2f w2 = seg_writhe_pair(sidx[sA + 2048], sidx[sA + 3072], sx, sy, sz);
        swr[sA]        = w1.x;
        swr[sA + 1024] = w1.y;
        swr[sA + 2048] = w2.x;
        swr[sA + 3072] = w2.y;
    }
    __syncthreads();

    // ---------- Phase D: per-pair gather + dual store ----------
    float* ob = out + (size_t)b * OUT_PER_B;
    for (int p = t; p < NPAIR; p += BLOCK) {
        unsigned pk = spair[p];
        int bb = (int)(pk & 127u);
        int a  = (int)(pk >> 7);

        // segment ids for (i,j) in {a-1,a} x {b-1,b}; s(i,j)=base(i)+j-i-2
        int am1 = a - 1;
        int s00 = 125 * am1 - ((am1 * (am1 - 1)) >> 1) + bb - a - 2;  // (a-1, b-1)
        int s10 = s00 + 125 - a;                                      // (a,   b-1)

        bool v00 = (a >= 1) && (a <= 125) && (bb >= a + 2);
        bool v01 = (a >= 1) && (a <= 125) && (bb <= 126);
        bool v10 = (a <= 124) && (bb >= a + 3);
        bool v11 = (a <= 124) && (bb <= 126) && (bb >= a + 2);

        int c00 = min(max(s00,     0), NSEG - 1);
        int c01 = min(max(s00 + 1, 0), NSEG - 1);
        int c10 = min(max(s10,     0), NSEG - 1);
        int c11 = min(max(s10 + 1, 0), NSEG - 1);

        float sum = (v00 ? swr[c00] : 0.0f) + (v01 ? swr[c01] : 0.0f)
                  + (v10 ? swr[c10] : 0.0f) + (v11 ? swr[c11] : 0.0f);

        int k1 = 127 * a + bb - 1;   // (r,c) = (a,b), r < c
        int k2 = 127 * bb + a;       // (r,c) = (b,a), r > c
        ob[k1] = sum;
        ob[k2] = sum;
    }
}

extern "C" void kernel_launch(void* const* d_in, const int* in_sizes, int n_in,
                              void* d_out, int out_size, void* d_ws, size_t ws_size,
                              hipStream_t stream) {
    const float* xyz = (const float*)d_in[0];
    float*       out = (float*)d_out;

    int B = in_sizes[0] / (NATOMS * 3);   // 512 for the reference shapes
    writhe_fused<<<B, BLOCK, 0, stream>>>(xyz, out);
}